// Round 11
// baseline (232.088 us; speedup 1.0000x reference)
//
#include <hip/hip_runtime.h>

#define FIN 256
#define H1 8
#define C1 16
#define D1 128   // H1*C1
#define D2 40
#define D2P 48

#define BW_LOG 8
#define BWIDTH 256           // nodes per bucket
#define B1 256               // phase-1 blocks
#define NW 4                 // waves per phase-1 block
#define WSLOT (B1*NW)        // 1024 wave slots

typedef float f32x4 __attribute__((ext_vector_type(4)));
typedef short bf16x8 __attribute__((ext_vector_type(8)));

static __device__ __forceinline__ float lrelu(float x){ return fmaxf(x, 0.2f*x); }
static __device__ __forceinline__ float elu(float x){ return x > 0.f ? x : __expf(x) - 1.f; }
static __device__ __forceinline__ unsigned short f2bf(float f){      // RNE bf16
  unsigned u = __float_as_uint(f);
  return (unsigned short)((u + 0x7fffu + ((u >> 16) & 1u)) >> 16);
}
static __device__ __forceinline__ float bf_lo(unsigned v){ return __uint_as_float(v << 16); }
static __device__ __forceinline__ float bf_hi(unsigned v){ return __uint_as_float(v & 0xffff0000u); }
static __device__ __forceinline__ bf16x8 pack_bf8(float4 a, float4 b){
  bf16x8 r;
  r[0]=(short)f2bf(a.x); r[1]=(short)f2bf(a.y); r[2]=(short)f2bf(a.z); r[3]=(short)f2bf(a.w);
  r[4]=(short)f2bf(b.x); r[5]=(short)f2bf(b.y); r[6]=(short)f2bf(b.z); r[7]=(short)f2bf(b.w);
  return r;
}

// ---------------- CSR build: bucket sort, per-wave privatized histograms ----------------
__global__ __launch_bounds__(256) void p1count_k(const int* __restrict__ dst, int E, int NB,
                                                 int* __restrict__ blockHist){
  __shared__ int hist[NW][256];
  int blk = blockIdx.x, t = threadIdx.x, w = t >> 6;
  for (int i = t; i < NW*256; i += 256) ((int*)hist)[i] = 0;
  __syncthreads();
  int CH = (E + B1 - 1) / B1;
  int lo = blk*CH, hi = min(E, lo + CH);
  for (int i = lo + t; i < hi; i += 256)
    atomicAdd(&hist[w][dst[i] >> BW_LOG], 1);
  __syncthreads();
  for (int i = t; i < NB*NW; i += 256){
    int b = i >> 2, ww = i & 3;
    blockHist[b*WSLOT + blk*NW + ww] = hist[ww][b];
  }
}

// per-bucket exclusive scan over the WSLOT wave slots
__global__ __launch_bounds__(1024) void bscan_k(const int* __restrict__ blockHist,
                                                int* __restrict__ wOff, int* __restrict__ bucketCnt){
  __shared__ int s[WSLOT];
  int b = blockIdx.x, t = threadIdx.x;
  int v = blockHist[b*WSLOT + t];
  s[t] = v; __syncthreads();
  for (int o = 1; o < WSLOT; o <<= 1){
    int u = (t >= o) ? s[t-o] : 0;
    __syncthreads();
    s[t] += u;
    __syncthreads();
  }
  wOff[b*WSLOT + t] = s[t] - v;
  if (t == WSLOT-1) bucketCnt[b] = s[t];
}

// p1scatter: per-wave private cursors; inline bucket-count scan (NB <= 256)
__global__ __launch_bounds__(256) void p1scatter_k(const int* __restrict__ src, const int* __restrict__ dst,
                                                   int E, int NB,
                                                   const int* __restrict__ bucketCnt,
                                                   const int* __restrict__ wOff,
                                                   int* __restrict__ bucketEdges){
  __shared__ int curs[NW][256];
  __shared__ int sb[256];
  __shared__ int bstart[256];
  int blk = blockIdx.x, t = threadIdx.x, w = t >> 6;
  int v = (t < NB) ? bucketCnt[t] : 0;
  sb[t] = v; __syncthreads();
  for (int o = 1; o < 256; o <<= 1){
    int u = (t >= o) ? sb[t-o] : 0;
    __syncthreads();
    sb[t] += u;
    __syncthreads();
  }
  if (t < NB) bstart[t] = sb[t] - v;
  __syncthreads();
  for (int i = t; i < NB*NW; i += 256){
    int b = i >> 2, ww = i & 3;
    curs[ww][b] = bstart[b] + wOff[b*WSLOT + blk*NW + ww];
  }
  __syncthreads();
  int CH = (E + B1 - 1) / B1;
  int lo = blk*CH, hi = min(E, lo + CH);
  for (int i = lo + t; i < hi; i += 256){
    int dd = dst[i];
    int b = dd >> BW_LOG;
    int pos = atomicAdd(&curs[w][b], 1);
    bucketEdges[pos] = (src[i] << BW_LOG) | (dd & (BWIDTH-1));
  }
}

// p2: per-bucket deg/off/csr; per-wave privatized deg histograms
__global__ __launch_bounds__(BWIDTH) void p2_k(const int* __restrict__ bucketEdges,
                                               const int* __restrict__ bucketCnt, int NB,
                                               int* __restrict__ off, int* __restrict__ csr, int N){
  __shared__ int deg4[NW][BWIDTH];
  __shared__ int s[BWIDTH];
  __shared__ int cur[BWIDTH];
  __shared__ int sb[BWIDTH];
  int b = blockIdx.x, t = threadIdx.x, w = t >> 6;
  int vc = (t < NB) ? bucketCnt[t] : 0;
  sb[t] = vc; __syncthreads();
  for (int o = 1; o < BWIDTH; o <<= 1){
    int u = (t >= o) ? sb[t-o] : 0;
    __syncthreads();
    sb[t] += u;
    __syncthreads();
  }
  int e0 = (b > 0) ? sb[b-1] : 0;
  int e1 = sb[b];
  if (b == 0 && t == 0) off[N] = sb[NB-1];
  for (int i = t; i < NW*BWIDTH; i += BWIDTH) ((int*)deg4)[i] = 0;
  __syncthreads();
  for (int i = e0 + t; i < e1; i += BWIDTH)
    atomicAdd(&deg4[w][bucketEdges[i] & (BWIDTH-1)], 1);
  __syncthreads();
  int v = deg4[0][t] + deg4[1][t] + deg4[2][t] + deg4[3][t];
  s[t] = v; __syncthreads();
  for (int o = 1; o < BWIDTH; o <<= 1){
    int u = (t >= o) ? s[t-o] : 0;
    __syncthreads();
    s[t] += u;
    __syncthreads();
  }
  int excl = s[t] - v;
  int node = b*BWIDTH + t;
  if (node < N) off[node] = e0 + excl;
  cur[t] = excl;
  __syncthreads();
  for (int i = e0 + t; i < e1; i += BWIDTH){
    int pk = bucketEdges[i];
    int p = atomicAdd(&cur[pk & (BWIDTH-1)], 1);
    csr[e0 + p] = pk >> BW_LOG;
  }
}

// ---------------- W1T: [256][128] fp32 -> [128][256] bf16 ----------------
__global__ __launch_bounds__(256) void wt_k(const float* __restrict__ W, unsigned short* __restrict__ WT){
  int n = blockIdx.x;       // 0..127
  int k = threadIdx.x;      // 0..255
  WT[n*FIN + k] = f2bf(W[(size_t)k*D1 + n]);
}

// ---------------- W2T: [128][40] fp32 -> [48][128] bf16 ----------------
__global__ __launch_bounds__(128) void wt2_k(const float* __restrict__ W2, unsigned short* __restrict__ W2T){
  int c = blockIdx.x;       // 0..47
  int k = threadIdx.x;      // 0..127
  float v = (c < D2) ? W2[(size_t)k*D2 + c] : 0.f;
  W2T[c*D1 + k] = f2bf(v);
}

// ---------------- GEMM1 via MFMA ----------------
__global__ __launch_bounds__(256) void gemm1_mfma(const float* __restrict__ x,
    const unsigned short* __restrict__ W1T,
    const float* __restrict__ attS, const float* __restrict__ attD,
    unsigned short* __restrict__ h1b, float* __restrict__ aS, float* __restrict__ aD, int N){
  int tid = threadIdx.x;
  int w = tid >> 6, lane = tid & 63;
  int lr = lane & 15, lg = lane >> 4;
  int wm = w >> 1, wn = w & 1;
  int m0 = blockIdx.x * 64;

  int rowA[2];
  #pragma unroll
  for (int mi=0;mi<2;mi++){
    int r = m0 + wm*32 + mi*16 + lr;
    rowA[mi] = (r < N) ? r : (N-1);
  }

  f32x4 acc[2][4];
  #pragma unroll
  for (int mi=0;mi<2;mi++)
    #pragma unroll
    for (int ni=0;ni<4;ni++) acc[mi][ni] = (f32x4){0.f,0.f,0.f,0.f};

  #pragma unroll
  for (int ks = 0; ks < 8; ++ks){
    int k0 = ks*32 + lg*8;
    bf16x8 a[2], b[4];
    #pragma unroll
    for (int mi=0;mi<2;mi++){
      const float* px = x + (size_t)rowA[mi]*FIN + k0;
      float4 v0 = *(const float4*)px;
      float4 v1 = *(const float4*)(px+4);
      a[mi] = pack_bf8(v0, v1);
    }
    #pragma unroll
    for (int ni=0;ni<4;ni++){
      int col = wn*64 + ni*16 + lr;
      b[ni] = *(const bf16x8*)(W1T + (size_t)col*FIN + k0);
    }
    #pragma unroll
    for (int mi=0;mi<2;mi++)
      #pragma unroll
      for (int ni=0;ni<4;ni++)
        acc[mi][ni] = __builtin_amdgcn_mfma_f32_16x16x32_bf16(a[mi], b[ni], acc[mi][ni], 0, 0, 0);
  }

  #pragma unroll
  for (int mi=0;mi<2;mi++){
    #pragma unroll
    for (int ni=0;ni<4;ni++){
      int h = wn*4 + ni;
      int col = wn*64 + ni*16 + lr;
      float sS = attS[h*C1 + lr], sD = attD[h*C1 + lr];
      #pragma unroll
      for (int i=0;i<4;i++){
        int row = m0 + wm*32 + mi*16 + 4*lg + i;
        float v = acc[mi][ni][i];
        float pS = v*sS, pD = v*sD;
        pS += __shfl_xor(pS, 1); pD += __shfl_xor(pD, 1);
        pS += __shfl_xor(pS, 2); pD += __shfl_xor(pD, 2);
        pS += __shfl_xor(pS, 4); pD += __shfl_xor(pD, 4);
        pS += __shfl_xor(pS, 8); pD += __shfl_xor(pD, 8);
        if (row < N){
          h1b[(size_t)row*D1 + col] = f2bf(v);
          if (lr == 0){ aS[row*H1 + h] = pS; aD[row*H1 + h] = pD; }
        }
      }
    }
  }
}

// ---------------- GEMM2 via MFMA, pure bf16 ----------------
__global__ __launch_bounds__(256) void gemm2_mfma(const unsigned short* __restrict__ x2b,
    const unsigned short* __restrict__ W2T,
    const float* __restrict__ attS2, const float* __restrict__ attD2,
    unsigned short* __restrict__ h2b, float* __restrict__ aS2, float* __restrict__ aD2, int N){
  int tid = threadIdx.x;
  int w = tid >> 6, lane = tid & 63;
  int lr = lane & 15, lg = lane >> 4;
  int m0 = blockIdx.x*128 + w*32;

  int rowA[2];
  #pragma unroll
  for (int mi=0;mi<2;mi++){
    int r = m0 + mi*16 + lr;
    rowA[mi] = (r < N) ? r : (N-1);
  }

  f32x4 acc[2][3];
  #pragma unroll
  for (int mi=0;mi<2;mi++)
    #pragma unroll
    for (int ni=0;ni<3;ni++) acc[mi][ni] = (f32x4){0.f,0.f,0.f,0.f};

  #pragma unroll
  for (int ks = 0; ks < 4; ++ks){
    int k0 = ks*32 + lg*8;
    bf16x8 a[2], b[3];
    #pragma unroll
    for (int mi=0;mi<2;mi++)
      a[mi] = *(const bf16x8*)(x2b + (size_t)rowA[mi]*D1 + k0);
    #pragma unroll
    for (int ni=0;ni<3;ni++){
      int col = ni*16 + lr;
      b[ni] = *(const bf16x8*)(W2T + (size_t)col*D1 + k0);
    }
    #pragma unroll
    for (int mi=0;mi<2;mi++)
      #pragma unroll
      for (int ni=0;ni<3;ni++)
        acc[mi][ni] = __builtin_amdgcn_mfma_f32_16x16x32_bf16(a[mi], b[ni], acc[mi][ni], 0, 0, 0);
  }

  float attSv[3], attDv[3];
  #pragma unroll
  for (int ni=0;ni<3;ni++){
    int col = ni*16 + lr;
    attSv[ni] = (col < D2) ? attS2[col] : 0.f;
    attDv[ni] = (col < D2) ? attD2[col] : 0.f;
  }
  #pragma unroll
  for (int mi=0;mi<2;mi++){
    #pragma unroll
    for (int i=0;i<4;i++){
      int row = m0 + mi*16 + 4*lg + i;
      float pS = 0.f, pD = 0.f;
      #pragma unroll
      for (int ni=0;ni<3;ni++){
        pS += acc[mi][ni][i]*attSv[ni];
        pD += acc[mi][ni][i]*attDv[ni];
      }
      pS += __shfl_xor(pS, 1); pD += __shfl_xor(pD, 1);
      pS += __shfl_xor(pS, 2); pD += __shfl_xor(pD, 2);
      pS += __shfl_xor(pS, 4); pD += __shfl_xor(pD, 4);
      pS += __shfl_xor(pS, 8); pD += __shfl_xor(pD, 8);
      if (row < N){
        #pragma unroll
        for (int ni=0;ni<3;ni++){
          int col = ni*16 + lr;
          if (col < D2) h2b[(size_t)row*D2 + col] = f2bf(acc[mi][ni][i]);
        }
        if (lr == 0){ aS2[row] = pS; aD2[row] = pD; }
      }
    }
  }
}

// ---------------- node1: softmax aggregation over bf16 h1 -> bf16 x2 (R9 form) ----------------
__global__ __launch_bounds__(64) void node1_k(const unsigned short* __restrict__ h1b,
    const float* __restrict__ aS, const float* __restrict__ aD,
    const int* __restrict__ off, const int* __restrict__ csr,
    const float* __restrict__ b1, unsigned short* __restrict__ x2b, int N){
  int n = blockIdx.x;
  int lane = threadIdx.x;
  int c = lane*2;                 // channels c, c+1
  int h = lane >> 3;              // head = c/16
  float ad = aD[n*H1+h];
  float p = __expf(lrelu(aS[n*H1+h] + ad));   // self loop
  float d = p;
  unsigned hv = *(const unsigned*)&h1b[(size_t)n*D1 + c];
  float acc0 = p*bf_lo(hv), acc1 = p*bf_hi(hv);
  int i = off[n], e = off[n+1];
  for (; i < e && (i & 3); ++i){
    int s = csr[i];
    float pp = __expf(lrelu(aS[s*H1+h] + ad));
    unsigned vv = *(const unsigned*)&h1b[(size_t)s*D1 + c];
    d += pp; acc0 += pp*bf_lo(vv); acc1 += pp*bf_hi(vv);
  }
  for (; i+8 <= e; i += 8){
    int4 ca = *(const int4*)&csr[i];
    int4 cb = *(const int4*)&csr[i+4];
    int s[8] = {ca.x,ca.y,ca.z,ca.w,cb.x,cb.y,cb.z,cb.w};
    float a[8]; unsigned v[8];
    #pragma unroll
    for (int u=0;u<8;u++) a[u] = aS[s[u]*H1+h];
    #pragma unroll
    for (int u=0;u<8;u++) v[u] = *(const unsigned*)&h1b[(size_t)s[u]*D1 + c];
    #pragma unroll
    for (int u=0;u<8;u++){
      float pp = __expf(lrelu(a[u]+ad));
      d += pp; acc0 += pp*bf_lo(v[u]); acc1 += pp*bf_hi(v[u]);
    }
  }
  for (; i < e; ++i){
    int s = csr[i];
    float pp = __expf(lrelu(aS[s*H1+h] + ad));
    unsigned vv = *(const unsigned*)&h1b[(size_t)s*D1 + c];
    d += pp; acc0 += pp*bf_lo(vv); acc1 += pp*bf_hi(vv);
  }
  float inv = 1.f/d;
  float o0 = elu(acc0*inv + b1[c]);
  float o1 = elu(acc1*inv + b1[c+1]);
  unsigned pk = (unsigned)f2bf(o0) | ((unsigned)f2bf(o1) << 16);
  *(unsigned*)&x2b[(size_t)n*D1 + c] = pk;
}

// ---------------- node2: softmax aggregation over bf16 h2 (R9 form) ----------------
__global__ __launch_bounds__(64) void node2_k(const unsigned short* __restrict__ h2b,
    const float* __restrict__ aS2, const float* __restrict__ aD2,
    const int* __restrict__ off, const int* __restrict__ csr,
    const float* __restrict__ b2, float* __restrict__ out, int N){
  int n = blockIdx.x;
  int lane = threadIdx.x;
  bool act = lane < 20;
  int c = lane*2;
  float ad = aD2[n];
  float ps = __expf(lrelu(aS2[n] + ad));   // self loop
  float d = ps;
  float acc0 = 0.f, acc1 = 0.f;
  if (act){
    unsigned v = *(const unsigned*)&h2b[(size_t)n*D2 + c];
    acc0 = ps*bf_lo(v); acc1 = ps*bf_hi(v);
  }
  int i = off[n], e = off[n+1];
  for (; i < e && (i & 3); ++i){
    int s = csr[i];
    float pp = __expf(lrelu(aS2[s] + ad));
    d += pp;
    if (act){
      unsigned vv = *(const unsigned*)&h2b[(size_t)s*D2 + c];
      acc0 += pp*bf_lo(vv); acc1 += pp*bf_hi(vv);
    }
  }
  for (; i+8 <= e; i += 8){
    int4 ca = *(const int4*)&csr[i];
    int4 cb = *(const int4*)&csr[i+4];
    int s[8] = {ca.x,ca.y,ca.z,ca.w,cb.x,cb.y,cb.z,cb.w};
    float a[8]; unsigned v[8];
    #pragma unroll
    for (int u=0;u<8;u++) a[u] = aS2[s[u]];
    if (act){
      #pragma unroll
      for (int u=0;u<8;u++) v[u] = *(const unsigned*)&h2b[(size_t)s[u]*D2 + c];
    } else {
      #pragma unroll
      for (int u=0;u<8;u++) v[u] = 0u;
    }
    #pragma unroll
    for (int u=0;u<8;u++){
      float pp = __expf(lrelu(a[u]+ad));
      d += pp; acc0 += pp*bf_lo(v[u]); acc1 += pp*bf_hi(v[u]);
    }
  }
  for (; i < e; ++i){
    int s = csr[i];
    float pp = __expf(lrelu(aS2[s] + ad));
    d += pp;
    if (act){
      unsigned vv = *(const unsigned*)&h2b[(size_t)s*D2 + c];
      acc0 += pp*bf_lo(vv); acc1 += pp*bf_hi(vv);
    }
  }
  if (act){
    float inv = 1.f/d;
    out[(size_t)n*D2 + c]     = acc0*inv + b2[c];
    out[(size_t)n*D2 + c + 1] = acc1*inv + b2[c+1];
  }
}

extern "C" void kernel_launch(void* const* d_in, const int* in_sizes, int n_in,
                              void* d_out, int out_size, void* d_ws, size_t ws_size,
                              hipStream_t stream){
  const float* x     = (const float*)d_in[0];
  const int*   ei    = (const int*)d_in[1];
  const float* W1    = (const float*)d_in[2];
  const float* attS1 = (const float*)d_in[3];
  const float* attD1 = (const float*)d_in[4];
  const float* b1    = (const float*)d_in[5];
  const float* W2    = (const float*)d_in[6];
  const float* attS2 = (const float*)d_in[7];
  const float* attD2 = (const float*)d_in[8];
  const float* b2    = (const float*)d_in[9];
  float* out = (float*)d_out;

  int N = in_sizes[0] / FIN;   // 50000
  int E = in_sizes[1] / 2;     // 1600000
  const int* src = ei;
  const int* dst = ei + E;
  int NB = (N + BWIDTH - 1) >> BW_LOG;    // 196

  char* ws = (char*)d_ws;
  size_t o = 0;
  auto alloc = [&](size_t bytes) -> void* {
    void* p = ws + o;
    o += (bytes + 255) & ~size_t(255);
    return p;
  };
  unsigned short* h1b = (unsigned short*)alloc((size_t)N*D1*sizeof(unsigned short));
  unsigned short* x2b = (unsigned short*)alloc((size_t)N*D1*sizeof(unsigned short));
  unsigned short* h2b = (unsigned short*)alloc((size_t)N*D2*sizeof(unsigned short));
  float* aS1   = (float*)alloc((size_t)N*H1*sizeof(float));
  float* aD1   = (float*)alloc((size_t)N*H1*sizeof(float));
  float* aS2   = (float*)alloc((size_t)N*sizeof(float));
  float* aD2   = (float*)alloc((size_t)N*sizeof(float));
  int*   off   = (int*)alloc((size_t)(N+1)*sizeof(int));
  int*   csr   = (int*)alloc((size_t)E*sizeof(int));
  int*   blockHist   = (int*)alloc((size_t)NB*WSLOT*sizeof(int));
  int*   wOff        = (int*)alloc((size_t)NB*WSLOT*sizeof(int));
  int*   bucketCnt   = (int*)alloc((size_t)NB*sizeof(int));
  int*   bucketEdges = (int*)alloc((size_t)E*sizeof(int));
  unsigned short* W1T = (unsigned short*)alloc((size_t)D1*FIN*sizeof(unsigned short));
  unsigned short* W2T = (unsigned short*)alloc((size_t)D2P*D1*sizeof(unsigned short));

  p1count_k<<<B1, 256, 0, stream>>>(dst, E, NB, blockHist);
  bscan_k<<<NB, WSLOT, 0, stream>>>(blockHist, wOff, bucketCnt);
  p1scatter_k<<<B1, 256, 0, stream>>>(src, dst, E, NB, bucketCnt, wOff, bucketEdges);
  p2_k<<<NB, BWIDTH, 0, stream>>>(bucketEdges, bucketCnt, NB, off, csr, N);
  wt_k<<<D1, 256, 0, stream>>>(W1, W1T);
  wt2_k<<<D2P, 128, 0, stream>>>(W2, W2T);
  gemm1_mfma<<<(N+63)/64, 256, 0, stream>>>(x, W1T, attS1, attD1, h1b, aS1, aD1, N);
  node1_k<<<N, 64, 0, stream>>>(h1b, aS1, aD1, off, csr, b1, x2b, N);
  gemm2_mfma<<<(N+127)/128, 256, 0, stream>>>(x2b, W2T, attS2, attD2, h2b, aS2, aD2, N);
  node2_k<<<N, 64, 0, stream>>>(h2b, aS2, aD2, off, csr, b2, out, N);
}

// Round 12
// 206.035 us; speedup vs baseline: 1.1264x; 1.1264x over previous
//
#include <hip/hip_runtime.h>

#define FIN 256
#define H1 8
#define C1 16
#define D1 128   // H1*C1
#define D2 40
#define D2P 48

#define BW_LOG 8
#define BWIDTH 256           // nodes per bucket
#define B1 512               // phase-1 scatter blocks

typedef float f32x4 __attribute__((ext_vector_type(4)));
typedef short bf16x8 __attribute__((ext_vector_type(8)));

static __device__ __forceinline__ float lrelu(float x){ return fmaxf(x, 0.2f*x); }
static __device__ __forceinline__ float elu(float x){ return x > 0.f ? x : __expf(x) - 1.f; }
static __device__ __forceinline__ unsigned short f2bf(float f){      // RNE bf16
  unsigned u = __float_as_uint(f);
  return (unsigned short)((u + 0x7fffu + ((u >> 16) & 1u)) >> 16);
}
static __device__ __forceinline__ float bf_lo(unsigned v){ return __uint_as_float(v << 16); }
static __device__ __forceinline__ float bf_hi(unsigned v){ return __uint_as_float(v & 0xffff0000u); }
static __device__ __forceinline__ bf16x8 pack_bf8(float4 a, float4 b){
  bf16x8 r;
  r[0]=(short)f2bf(a.x); r[1]=(short)f2bf(a.y); r[2]=(short)f2bf(a.z); r[3]=(short)f2bf(a.w);
  r[4]=(short)f2bf(b.x); r[5]=(short)f2bf(b.y); r[6]=(short)f2bf(b.z); r[7]=(short)f2bf(b.w);
  return r;
}

// ---------------- F1: p1count (blocks 0..B1) ∪ wt (next 128) ∪ wt2 (next 24) ----------------
__global__ __launch_bounds__(256) void f1_k(const int* __restrict__ dst, int E, int NB,
                                            int* __restrict__ blockHist,
                                            const float* __restrict__ W1, unsigned short* __restrict__ W1T,
                                            const float* __restrict__ W2, unsigned short* __restrict__ W2T){
  int b = blockIdx.x, t = threadIdx.x;
  if (b < B1){
    __shared__ int hist[256];
    hist[t] = 0;
    __syncthreads();
    int CH = (E + B1 - 1) / B1;
    int lo = b*CH, hi = min(E, lo + CH);
    for (int i = lo + t; i < hi; i += 256)
      atomicAdd(&hist[dst[i] >> BW_LOG], 1);
    __syncthreads();
    for (int i = t; i < NB; i += 256) blockHist[i*B1 + b] = hist[i];
  } else if (b < B1 + 128){
    int n = b - B1;
    W1T[n*FIN + t] = f2bf(W1[(size_t)t*D1 + n]);
  } else {
    int c = (b - B1 - 128)*2 + (t >> 7);
    int k = t & 127;
    float v = (c < D2) ? W2[(size_t)k*D2 + c] : 0.f;
    W2T[c*D1 + k] = f2bf(v);
  }
}

// per-bucket exclusive scan over B1 blocks
__global__ __launch_bounds__(B1) void bscan_k(const int* __restrict__ blockHist,
                                              int* __restrict__ wOff, int* __restrict__ bucketCnt){
  __shared__ int s[B1];
  int b = blockIdx.x, t = threadIdx.x;
  int v = blockHist[b*B1 + t];
  s[t] = v; __syncthreads();
  for (int o = 1; o < B1; o <<= 1){
    int u = (t >= o) ? s[t-o] : 0;
    __syncthreads();
    s[t] += u;
    __syncthreads();
  }
  wOff[b*B1 + t] = s[t] - v;
  if (t == B1-1) bucketCnt[b] = s[t];
}

// ---------------- F3: gemm1 (blocks 0..G1) ∪ p1scatter (blocks G1..G1+B1) ----------------
__global__ __launch_bounds__(256) void f3_k(
    // gemm1 args
    const float* __restrict__ x, const unsigned short* __restrict__ W1T,
    const float* __restrict__ attS, const float* __restrict__ attD,
    unsigned short* __restrict__ h1b, float* __restrict__ aS, float* __restrict__ aD, int N, int G1,
    // p1scatter args
    const int* __restrict__ src, const int* __restrict__ dst, int E, int NB,
    const int* __restrict__ bucketCnt, const int* __restrict__ wOff, int* __restrict__ bucketEdges){
  int tid = threadIdx.x;
  if ((int)blockIdx.x >= G1){
    // ---- p1scatter ----
    __shared__ int curs[256];
    __shared__ int sb[256];
    int blk = blockIdx.x - G1;
    int v = (tid < NB) ? bucketCnt[tid] : 0;
    sb[tid] = v; __syncthreads();
    for (int o = 1; o < 256; o <<= 1){
      int u = (tid >= o) ? sb[tid-o] : 0;
      __syncthreads();
      sb[tid] += u;
      __syncthreads();
    }
    if (tid < NB) curs[tid] = (sb[tid] - v) + wOff[tid*B1 + blk];
    __syncthreads();
    int CH = (E + B1 - 1) / B1;
    int lo = blk*CH, hi = min(E, lo + CH);
    for (int i = lo + tid; i < hi; i += 256){
      int dd = dst[i];
      int b = dd >> BW_LOG;
      int pos = atomicAdd(&curs[b], 1);
      bucketEdges[pos] = (src[i] << BW_LOG) | (dd & (BWIDTH-1));
    }
    return;
  }
  // ---- gemm1 ----
  int w = tid >> 6, lane = tid & 63;
  int lr = lane & 15, lg = lane >> 4;
  int wm = w >> 1, wn = w & 1;
  int m0 = blockIdx.x * 64;

  int rowA[2];
  #pragma unroll
  for (int mi=0;mi<2;mi++){
    int r = m0 + wm*32 + mi*16 + lr;
    rowA[mi] = (r < N) ? r : (N-1);
  }

  f32x4 acc[2][4];
  #pragma unroll
  for (int mi=0;mi<2;mi++)
    #pragma unroll
    for (int ni=0;ni<4;ni++) acc[mi][ni] = (f32x4){0.f,0.f,0.f,0.f};

  #pragma unroll
  for (int ks = 0; ks < 8; ++ks){
    int k0 = ks*32 + lg*8;
    bf16x8 a[2], b[4];
    #pragma unroll
    for (int mi=0;mi<2;mi++){
      const float* px = x + (size_t)rowA[mi]*FIN + k0;
      float4 v0 = *(const float4*)px;
      float4 v1 = *(const float4*)(px+4);
      a[mi] = pack_bf8(v0, v1);
    }
    #pragma unroll
    for (int ni=0;ni<4;ni++){
      int col = wn*64 + ni*16 + lr;
      b[ni] = *(const bf16x8*)(W1T + (size_t)col*FIN + k0);
    }
    #pragma unroll
    for (int mi=0;mi<2;mi++)
      #pragma unroll
      for (int ni=0;ni<4;ni++)
        acc[mi][ni] = __builtin_amdgcn_mfma_f32_16x16x32_bf16(a[mi], b[ni], acc[mi][ni], 0, 0, 0);
  }

  #pragma unroll
  for (int mi=0;mi<2;mi++){
    #pragma unroll
    for (int ni=0;ni<4;ni++){
      int h = wn*4 + ni;
      int col = wn*64 + ni*16 + lr;
      float sS = attS[h*C1 + lr], sD = attD[h*C1 + lr];
      #pragma unroll
      for (int i=0;i<4;i++){
        int row = m0 + wm*32 + mi*16 + 4*lg + i;
        float v = acc[mi][ni][i];
        float pS = v*sS, pD = v*sD;
        pS += __shfl_xor(pS, 1); pD += __shfl_xor(pD, 1);
        pS += __shfl_xor(pS, 2); pD += __shfl_xor(pD, 2);
        pS += __shfl_xor(pS, 4); pD += __shfl_xor(pD, 4);
        pS += __shfl_xor(pS, 8); pD += __shfl_xor(pD, 8);
        if (row < N){
          h1b[(size_t)row*D1 + col] = f2bf(v);
          if (lr == 0){ aS[row*H1 + h] = pS; aD[row*H1 + h] = pD; }
        }
      }
    }
  }
}

// p2 with inline bucket-count scan; also writes off[N]  (R9-exact)
__global__ __launch_bounds__(BWIDTH) void p2_k(const int* __restrict__ bucketEdges,
                                               const int* __restrict__ bucketCnt, int NB,
                                               int* __restrict__ off, int* __restrict__ csr, int N){
  __shared__ int deg[BWIDTH];
  __shared__ int s[BWIDTH];
  __shared__ int cur[BWIDTH];
  __shared__ int sb[BWIDTH];
  int b = blockIdx.x, t = threadIdx.x;
  int vc = (t < NB) ? bucketCnt[t] : 0;
  sb[t] = vc; __syncthreads();
  for (int o = 1; o < BWIDTH; o <<= 1){
    int u = (t >= o) ? sb[t-o] : 0;
    __syncthreads();
    sb[t] += u;
    __syncthreads();
  }
  int e0 = (b > 0) ? sb[b-1] : 0;
  int e1 = sb[b];
  if (b == 0 && t == 0) off[N] = sb[NB-1];
  deg[t] = 0;
  __syncthreads();
  for (int i = e0 + t; i < e1; i += BWIDTH)
    atomicAdd(&deg[bucketEdges[i] & (BWIDTH-1)], 1);
  __syncthreads();
  int v = deg[t];
  s[t] = v; __syncthreads();
  for (int o = 1; o < BWIDTH; o <<= 1){
    int u = (t >= o) ? s[t-o] : 0;
    __syncthreads();
    s[t] += u;
    __syncthreads();
  }
  int excl = s[t] - v;
  int node = b*BWIDTH + t;
  if (node < N) off[node] = e0 + excl;
  cur[t] = excl;
  __syncthreads();
  for (int i = e0 + t; i < e1; i += BWIDTH){
    int pk = bucketEdges[i];
    int p = atomicAdd(&cur[pk & (BWIDTH-1)], 1);
    csr[e0 + p] = pk >> BW_LOG;
  }
}

// ---------------- GEMM2 via MFMA, pure bf16 ----------------
__global__ __launch_bounds__(256) void gemm2_mfma(const unsigned short* __restrict__ x2b,
    const unsigned short* __restrict__ W2T,
    const float* __restrict__ attS2, const float* __restrict__ attD2,
    unsigned short* __restrict__ h2b, float* __restrict__ aS2, float* __restrict__ aD2, int N){
  int tid = threadIdx.x;
  int w = tid >> 6, lane = tid & 63;
  int lr = lane & 15, lg = lane >> 4;
  int m0 = blockIdx.x*128 + w*32;

  int rowA[2];
  #pragma unroll
  for (int mi=0;mi<2;mi++){
    int r = m0 + mi*16 + lr;
    rowA[mi] = (r < N) ? r : (N-1);
  }

  f32x4 acc[2][3];
  #pragma unroll
  for (int mi=0;mi<2;mi++)
    #pragma unroll
    for (int ni=0;ni<3;ni++) acc[mi][ni] = (f32x4){0.f,0.f,0.f,0.f};

  #pragma unroll
  for (int ks = 0; ks < 4; ++ks){
    int k0 = ks*32 + lg*8;
    bf16x8 a[2], b[3];
    #pragma unroll
    for (int mi=0;mi<2;mi++)
      a[mi] = *(const bf16x8*)(x2b + (size_t)rowA[mi]*D1 + k0);
    #pragma unroll
    for (int ni=0;ni<3;ni++){
      int col = ni*16 + lr;
      b[ni] = *(const bf16x8*)(W2T + (size_t)col*D1 + k0);
    }
    #pragma unroll
    for (int mi=0;mi<2;mi++)
      #pragma unroll
      for (int ni=0;ni<3;ni++)
        acc[mi][ni] = __builtin_amdgcn_mfma_f32_16x16x32_bf16(a[mi], b[ni], acc[mi][ni], 0, 0, 0);
  }

  float attSv[3], attDv[3];
  #pragma unroll
  for (int ni=0;ni<3;ni++){
    int col = ni*16 + lr;
    attSv[ni] = (col < D2) ? attS2[col] : 0.f;
    attDv[ni] = (col < D2) ? attD2[col] : 0.f;
  }
  #pragma unroll
  for (int mi=0;mi<2;mi++){
    #pragma unroll
    for (int i=0;i<4;i++){
      int row = m0 + mi*16 + 4*lg + i;
      float pS = 0.f, pD = 0.f;
      #pragma unroll
      for (int ni=0;ni<3;ni++){
        pS += acc[mi][ni][i]*attSv[ni];
        pD += acc[mi][ni][i]*attDv[ni];
      }
      pS += __shfl_xor(pS, 1); pD += __shfl_xor(pD, 1);
      pS += __shfl_xor(pS, 2); pD += __shfl_xor(pD, 2);
      pS += __shfl_xor(pS, 4); pD += __shfl_xor(pD, 4);
      pS += __shfl_xor(pS, 8); pD += __shfl_xor(pD, 8);
      if (row < N){
        #pragma unroll
        for (int ni=0;ni<3;ni++){
          int col = ni*16 + lr;
          if (col < D2) h2b[(size_t)row*D2 + col] = f2bf(acc[mi][ni][i]);
        }
        if (lr == 0){ aS2[row] = pS; aD2[row] = pD; }
      }
    }
  }
}

// ---------------- node1: softmax aggregation over bf16 h1 -> bf16 x2 ----------------
__global__ __launch_bounds__(64) void node1_k(const unsigned short* __restrict__ h1b,
    const float* __restrict__ aS, const float* __restrict__ aD,
    const int* __restrict__ off, const int* __restrict__ csr,
    const float* __restrict__ b1, unsigned short* __restrict__ x2b, int N){
  int n = blockIdx.x;
  int lane = threadIdx.x;
  int c = lane*2;                 // channels c, c+1
  int h = lane >> 3;              // head = c/16
  float ad = aD[n*H1+h];
  float p = __expf(lrelu(aS[n*H1+h] + ad));   // self loop
  float d = p;
  unsigned hv = *(const unsigned*)&h1b[(size_t)n*D1 + c];
  float acc0 = p*bf_lo(hv), acc1 = p*bf_hi(hv);
  int i = off[n], e = off[n+1];
  for (; i < e && (i & 3); ++i){
    int s = csr[i];
    float pp = __expf(lrelu(aS[s*H1+h] + ad));
    unsigned vv = *(const unsigned*)&h1b[(size_t)s*D1 + c];
    d += pp; acc0 += pp*bf_lo(vv); acc1 += pp*bf_hi(vv);
  }
  for (; i+8 <= e; i += 8){
    int4 ca = *(const int4*)&csr[i];
    int4 cb = *(const int4*)&csr[i+4];
    int s[8] = {ca.x,ca.y,ca.z,ca.w,cb.x,cb.y,cb.z,cb.w};
    float a[8]; unsigned v[8];
    #pragma unroll
    for (int u=0;u<8;u++) a[u] = aS[s[u]*H1+h];
    #pragma unroll
    for (int u=0;u<8;u++) v[u] = *(const unsigned*)&h1b[(size_t)s[u]*D1 + c];
    #pragma unroll
    for (int u=0;u<8;u++){
      float pp = __expf(lrelu(a[u]+ad));
      d += pp; acc0 += pp*bf_lo(v[u]); acc1 += pp*bf_hi(v[u]);
    }
  }
  for (; i < e; ++i){
    int s = csr[i];
    float pp = __expf(lrelu(aS[s*H1+h] + ad));
    unsigned vv = *(const unsigned*)&h1b[(size_t)s*D1 + c];
    d += pp; acc0 += pp*bf_lo(vv); acc1 += pp*bf_hi(vv);
  }
  float inv = 1.f/d;
  float o0 = elu(acc0*inv + b1[c]);
  float o1 = elu(acc1*inv + b1[c+1]);
  unsigned pk = (unsigned)f2bf(o0) | ((unsigned)f2bf(o1) << 16);
  *(unsigned*)&x2b[(size_t)n*D1 + c] = pk;
}

// ---------------- node2: softmax aggregation over bf16 h2 ----------------
__global__ __launch_bounds__(64) void node2_k(const unsigned short* __restrict__ h2b,
    const float* __restrict__ aS2, const float* __restrict__ aD2,
    const int* __restrict__ off, const int* __restrict__ csr,
    const float* __restrict__ b2, float* __restrict__ out, int N){
  int n = blockIdx.x;
  int lane = threadIdx.x;
  bool act = lane < 20;
  int c = lane*2;
  float ad = aD2[n];
  float ps = __expf(lrelu(aS2[n] + ad));   // self loop
  float d = ps;
  float acc0 = 0.f, acc1 = 0.f;
  if (act){
    unsigned v = *(const unsigned*)&h2b[(size_t)n*D2 + c];
    acc0 = ps*bf_lo(v); acc1 = ps*bf_hi(v);
  }
  int i = off[n], e = off[n+1];
  for (; i < e && (i & 3); ++i){
    int s = csr[i];
    float pp = __expf(lrelu(aS2[s] + ad));
    d += pp;
    if (act){
      unsigned vv = *(const unsigned*)&h2b[(size_t)s*D2 + c];
      acc0 += pp*bf_lo(vv); acc1 += pp*bf_hi(vv);
    }
  }
  for (; i+8 <= e; i += 8){
    int4 ca = *(const int4*)&csr[i];
    int4 cb = *(const int4*)&csr[i+4];
    int s[8] = {ca.x,ca.y,ca.z,ca.w,cb.x,cb.y,cb.z,cb.w};
    float a[8]; unsigned v[8];
    #pragma unroll
    for (int u=0;u<8;u++) a[u] = aS2[s[u]];
    if (act){
      #pragma unroll
      for (int u=0;u<8;u++) v[u] = *(const unsigned*)&h2b[(size_t)s[u]*D2 + c];
    } else {
      #pragma unroll
      for (int u=0;u<8;u++) v[u] = 0u;
    }
    #pragma unroll
    for (int u=0;u<8;u++){
      float pp = __expf(lrelu(a[u]+ad));
      d += pp; acc0 += pp*bf_lo(v[u]); acc1 += pp*bf_hi(v[u]);
    }
  }
  for (; i < e; ++i){
    int s = csr[i];
    float pp = __expf(lrelu(aS2[s] + ad));
    d += pp;
    if (act){
      unsigned vv = *(const unsigned*)&h2b[(size_t)s*D2 + c];
      acc0 += pp*bf_lo(vv); acc1 += pp*bf_hi(vv);
    }
  }
  if (act){
    float inv = 1.f/d;
    out[(size_t)n*D2 + c]     = acc0*inv + b2[c];
    out[(size_t)n*D2 + c + 1] = acc1*inv + b2[c+1];
  }
}

extern "C" void kernel_launch(void* const* d_in, const int* in_sizes, int n_in,
                              void* d_out, int out_size, void* d_ws, size_t ws_size,
                              hipStream_t stream){
  const float* x     = (const float*)d_in[0];
  const int*   ei    = (const int*)d_in[1];
  const float* W1    = (const float*)d_in[2];
  const float* attS1 = (const float*)d_in[3];
  const float* attD1 = (const float*)d_in[4];
  const float* b1    = (const float*)d_in[5];
  const float* W2    = (const float*)d_in[6];
  const float* attS2 = (const float*)d_in[7];
  const float* attD2 = (const float*)d_in[8];
  const float* b2    = (const float*)d_in[9];
  float* out = (float*)d_out;

  int N = in_sizes[0] / FIN;   // 50000
  int E = in_sizes[1] / 2;     // 1600000
  const int* src = ei;
  const int* dst = ei + E;
  int NB = (N + BWIDTH - 1) >> BW_LOG;    // 196

  char* ws = (char*)d_ws;
  size_t o = 0;
  auto alloc = [&](size_t bytes) -> void* {
    void* p = ws + o;
    o += (bytes + 255) & ~size_t(255);
    return p;
  };
  unsigned short* h1b = (unsigned short*)alloc((size_t)N*D1*sizeof(unsigned short));
  unsigned short* x2b = (unsigned short*)alloc((size_t)N*D1*sizeof(unsigned short));
  unsigned short* h2b = (unsigned short*)alloc((size_t)N*D2*sizeof(unsigned short));
  float* aS1   = (float*)alloc((size_t)N*H1*sizeof(float));
  float* aD1   = (float*)alloc((size_t)N*H1*sizeof(float));
  float* aS2   = (float*)alloc((size_t)N*sizeof(float));
  float* aD2   = (float*)alloc((size_t)N*sizeof(float));
  int*   off   = (int*)alloc((size_t)(N+1)*sizeof(int));
  int*   csr   = (int*)alloc((size_t)E*sizeof(int));
  int*   blockHist   = (int*)alloc((size_t)NB*B1*sizeof(int));
  int*   wOff        = (int*)alloc((size_t)NB*B1*sizeof(int));
  int*   bucketCnt   = (int*)alloc((size_t)NB*sizeof(int));
  int*   bucketEdges = (int*)alloc((size_t)E*sizeof(int));
  unsigned short* W1T = (unsigned short*)alloc((size_t)D1*FIN*sizeof(unsigned short));
  unsigned short* W2T = (unsigned short*)alloc((size_t)D2P*D1*sizeof(unsigned short));

  int G1 = (N + 63) / 64;      // gemm1 blocks = 782

  f1_k<<<B1 + 128 + 24, 256, 0, stream>>>(dst, E, NB, blockHist, W1, W1T, W2, W2T);
  bscan_k<<<NB, B1, 0, stream>>>(blockHist, wOff, bucketCnt);
  f3_k<<<G1 + B1, 256, 0, stream>>>(x, W1T, attS1, attD1, h1b, aS1, aD1, N, G1,
                                    src, dst, E, NB, bucketCnt, wOff, bucketEdges);
  p2_k<<<NB, BWIDTH, 0, stream>>>(bucketEdges, bucketCnt, NB, off, csr, N);
  node1_k<<<N, 64, 0, stream>>>(h1b, aS1, aD1, off, csr, b1, x2b, N);
  gemm2_mfma<<<(N+127)/128, 256, 0, stream>>>(x2b, W2T, attS2, attD2, h2b, aS2, aD2, N);
  node2_k<<<N, 64, 0, stream>>>(h2b, aS2, aD2, off, csr, b2, out, N);
}

// Round 13
// 186.348 us; speedup vs baseline: 1.2455x; 1.1056x over previous
//
#include <hip/hip_runtime.h>

#define FIN 256
#define H1 8
#define C1 16
#define D1 128   // H1*C1
#define D2 40
#define D2P 48

#define BW_LOG 8
#define BWIDTH 256           // nodes per bucket
#define B1 512               // phase-1 scatter blocks

typedef float f32x4 __attribute__((ext_vector_type(4)));
typedef short bf16x8 __attribute__((ext_vector_type(8)));

static __device__ __forceinline__ float lrelu(float x){ return fmaxf(x, 0.2f*x); }
static __device__ __forceinline__ float elu(float x){ return x > 0.f ? x : __expf(x) - 1.f; }
static __device__ __forceinline__ unsigned short f2bf(float f){      // RNE bf16
  unsigned u = __float_as_uint(f);
  return (unsigned short)((u + 0x7fffu + ((u >> 16) & 1u)) >> 16);
}
static __device__ __forceinline__ float bf_lo(unsigned v){ return __uint_as_float(v << 16); }
static __device__ __forceinline__ float bf_hi(unsigned v){ return __uint_as_float(v & 0xffff0000u); }
static __device__ __forceinline__ bf16x8 pack_bf8(float4 a, float4 b){
  bf16x8 r;
  r[0]=(short)f2bf(a.x); r[1]=(short)f2bf(a.y); r[2]=(short)f2bf(a.z); r[3]=(short)f2bf(a.w);
  r[4]=(short)f2bf(b.x); r[5]=(short)f2bf(b.y); r[6]=(short)f2bf(b.z); r[7]=(short)f2bf(b.w);
  return r;
}

// ---------------- F1: p1count (blocks 0..B1) ∪ wt (next 128) ∪ wt2 (next 24) ----------------
__global__ __launch_bounds__(256) void f1_k(const int* __restrict__ dst, int E, int NB,
                                            int* __restrict__ blockHist,
                                            const float* __restrict__ W1, unsigned short* __restrict__ W1T,
                                            const float* __restrict__ W2, unsigned short* __restrict__ W2T){
  int b = blockIdx.x, t = threadIdx.x;
  if (b < B1){
    __shared__ int hist[256];
    hist[t] = 0;
    __syncthreads();
    int CH = (E + B1 - 1) / B1;
    int lo = b*CH, hi = min(E, lo + CH);
    for (int i = lo + t; i < hi; i += 256)
      atomicAdd(&hist[dst[i] >> BW_LOG], 1);
    __syncthreads();
    for (int i = t; i < NB; i += 256) blockHist[i*B1 + b] = hist[i];
  } else if (b < B1 + 128){
    int n = b - B1;
    W1T[n*FIN + t] = f2bf(W1[(size_t)t*D1 + n]);
  } else {
    int c = (b - B1 - 128)*2 + (t >> 7);
    int k = t & 127;
    float v = (c < D2) ? W2[(size_t)k*D2 + c] : 0.f;
    W2T[c*D1 + k] = f2bf(v);
  }
}

// per-bucket exclusive scan over B1 blocks
__global__ __launch_bounds__(B1) void bscan_k(const int* __restrict__ blockHist,
                                              int* __restrict__ wOff, int* __restrict__ bucketCnt){
  __shared__ int s[B1];
  int b = blockIdx.x, t = threadIdx.x;
  int v = blockHist[b*B1 + t];
  s[t] = v; __syncthreads();
  for (int o = 1; o < B1; o <<= 1){
    int u = (t >= o) ? s[t-o] : 0;
    __syncthreads();
    s[t] += u;
    __syncthreads();
  }
  wOff[b*B1 + t] = s[t] - v;
  if (t == B1-1) bucketCnt[b] = s[t];
}

// ---------------- F3: p1scatter (blocks 0..B1, dispatched FIRST) ∪ gemm1 (blocks B1..) ----------------
__global__ __launch_bounds__(256) void f3_k(
    // gemm1 args
    const float* __restrict__ x, const unsigned short* __restrict__ W1T,
    const float* __restrict__ attS, const float* __restrict__ attD,
    unsigned short* __restrict__ h1b, float* __restrict__ aS, float* __restrict__ aD, int N,
    // p1scatter args
    const int* __restrict__ src, const int* __restrict__ dst, int E, int NB,
    const int* __restrict__ bucketCnt, const int* __restrict__ wOff, int* __restrict__ bucketEdges){
  int tid = threadIdx.x;
  if ((int)blockIdx.x < B1){
    // ---- p1scatter (critical path: p2 waits on this) ----
    __shared__ int curs[256];
    __shared__ int sb[256];
    int blk = blockIdx.x;
    int v = (tid < NB) ? bucketCnt[tid] : 0;
    sb[tid] = v; __syncthreads();
    for (int o = 1; o < 256; o <<= 1){
      int u = (tid >= o) ? sb[tid-o] : 0;
      __syncthreads();
      sb[tid] += u;
      __syncthreads();
    }
    if (tid < NB) curs[tid] = (sb[tid] - v) + wOff[tid*B1 + blk];
    __syncthreads();
    int CH = (E + B1 - 1) / B1;
    int lo = blk*CH, hi = min(E, lo + CH);
    for (int i = lo + tid; i < hi; i += 256){
      int dd = dst[i];
      int b = dd >> BW_LOG;
      int pos = atomicAdd(&curs[b], 1);
      bucketEdges[pos] = (src[i] << BW_LOG) | (dd & (BWIDTH-1));
    }
    return;
  }
  // ---- gemm1 ----
  int w = tid >> 6, lane = tid & 63;
  int lr = lane & 15, lg = lane >> 4;
  int wm = w >> 1, wn = w & 1;
  int m0 = ((int)blockIdx.x - B1) * 64;

  int rowA[2];
  #pragma unroll
  for (int mi=0;mi<2;mi++){
    int r = m0 + wm*32 + mi*16 + lr;
    rowA[mi] = (r < N) ? r : (N-1);
  }

  f32x4 acc[2][4];
  #pragma unroll
  for (int mi=0;mi<2;mi++)
    #pragma unroll
    for (int ni=0;ni<4;ni++) acc[mi][ni] = (f32x4){0.f,0.f,0.f,0.f};

  #pragma unroll
  for (int ks = 0; ks < 8; ++ks){
    int k0 = ks*32 + lg*8;
    bf16x8 a[2], b[4];
    #pragma unroll
    for (int mi=0;mi<2;mi++){
      const float* px = x + (size_t)rowA[mi]*FIN + k0;
      float4 v0 = *(const float4*)px;
      float4 v1 = *(const float4*)(px+4);
      a[mi] = pack_bf8(v0, v1);
    }
    #pragma unroll
    for (int ni=0;ni<4;ni++){
      int col = wn*64 + ni*16 + lr;
      b[ni] = *(const bf16x8*)(W1T + (size_t)col*FIN + k0);
    }
    #pragma unroll
    for (int mi=0;mi<2;mi++)
      #pragma unroll
      for (int ni=0;ni<4;ni++)
        acc[mi][ni] = __builtin_amdgcn_mfma_f32_16x16x32_bf16(a[mi], b[ni], acc[mi][ni], 0, 0, 0);
  }

  #pragma unroll
  for (int mi=0;mi<2;mi++){
    #pragma unroll
    for (int ni=0;ni<4;ni++){
      int h = wn*4 + ni;
      int col = wn*64 + ni*16 + lr;
      float sS = attS[h*C1 + lr], sD = attD[h*C1 + lr];
      #pragma unroll
      for (int i=0;i<4;i++){
        int row = m0 + wm*32 + mi*16 + 4*lg + i;
        float v = acc[mi][ni][i];
        float pS = v*sS, pD = v*sD;
        pS += __shfl_xor(pS, 1); pD += __shfl_xor(pD, 1);
        pS += __shfl_xor(pS, 2); pD += __shfl_xor(pD, 2);
        pS += __shfl_xor(pS, 4); pD += __shfl_xor(pD, 4);
        pS += __shfl_xor(pS, 8); pD += __shfl_xor(pD, 8);
        if (row < N){
          h1b[(size_t)row*D1 + col] = f2bf(v);
          if (lr == 0){ aS[row*H1 + h] = pS; aD[row*H1 + h] = pD; }
        }
      }
    }
  }
}

// p2 with inline bucket-count scan; also writes off[N]
__global__ __launch_bounds__(BWIDTH) void p2_k(const int* __restrict__ bucketEdges,
                                               const int* __restrict__ bucketCnt, int NB,
                                               int* __restrict__ off, int* __restrict__ csr, int N){
  __shared__ int deg[BWIDTH];
  __shared__ int s[BWIDTH];
  __shared__ int cur[BWIDTH];
  __shared__ int sb[BWIDTH];
  int b = blockIdx.x, t = threadIdx.x;
  int vc = (t < NB) ? bucketCnt[t] : 0;
  sb[t] = vc; __syncthreads();
  for (int o = 1; o < BWIDTH; o <<= 1){
    int u = (t >= o) ? sb[t-o] : 0;
    __syncthreads();
    sb[t] += u;
    __syncthreads();
  }
  int e0 = (b > 0) ? sb[b-1] : 0;
  int e1 = sb[b];
  if (b == 0 && t == 0) off[N] = sb[NB-1];
  deg[t] = 0;
  __syncthreads();
  for (int i = e0 + t; i < e1; i += BWIDTH)
    atomicAdd(&deg[bucketEdges[i] & (BWIDTH-1)], 1);
  __syncthreads();
  int v = deg[t];
  s[t] = v; __syncthreads();
  for (int o = 1; o < BWIDTH; o <<= 1){
    int u = (t >= o) ? s[t-o] : 0;
    __syncthreads();
    s[t] += u;
    __syncthreads();
  }
  int excl = s[t] - v;
  int node = b*BWIDTH + t;
  if (node < N) off[node] = e0 + excl;
  cur[t] = excl;
  __syncthreads();
  for (int i = e0 + t; i < e1; i += BWIDTH){
    int pk = bucketEdges[i];
    int p = atomicAdd(&cur[pk & (BWIDTH-1)], 1);
    csr[e0 + p] = pk >> BW_LOG;
  }
}

// ---------------- GEMM2 via MFMA, pure bf16 ----------------
__global__ __launch_bounds__(256) void gemm2_mfma(const unsigned short* __restrict__ x2b,
    const unsigned short* __restrict__ W2T,
    const float* __restrict__ attS2, const float* __restrict__ attD2,
    unsigned short* __restrict__ h2b, float* __restrict__ aS2, float* __restrict__ aD2, int N){
  int tid = threadIdx.x;
  int w = tid >> 6, lane = tid & 63;
  int lr = lane & 15, lg = lane >> 4;
  int m0 = blockIdx.x*128 + w*32;

  int rowA[2];
  #pragma unroll
  for (int mi=0;mi<2;mi++){
    int r = m0 + mi*16 + lr;
    rowA[mi] = (r < N) ? r : (N-1);
  }

  f32x4 acc[2][3];
  #pragma unroll
  for (int mi=0;mi<2;mi++)
    #pragma unroll
    for (int ni=0;ni<3;ni++) acc[mi][ni] = (f32x4){0.f,0.f,0.f,0.f};

  #pragma unroll
  for (int ks = 0; ks < 4; ++ks){
    int k0 = ks*32 + lg*8;
    bf16x8 a[2], b[3];
    #pragma unroll
    for (int mi=0;mi<2;mi++)
      a[mi] = *(const bf16x8*)(x2b + (size_t)rowA[mi]*D1 + k0);
    #pragma unroll
    for (int ni=0;ni<3;ni++){
      int col = ni*16 + lr;
      b[ni] = *(const bf16x8*)(W2T + (size_t)col*D1 + k0);
    }
    #pragma unroll
    for (int mi=0;mi<2;mi++)
      #pragma unroll
      for (int ni=0;ni<3;ni++)
        acc[mi][ni] = __builtin_amdgcn_mfma_f32_16x16x32_bf16(a[mi], b[ni], acc[mi][ni], 0, 0, 0);
  }

  float attSv[3], attDv[3];
  #pragma unroll
  for (int ni=0;ni<3;ni++){
    int col = ni*16 + lr;
    attSv[ni] = (col < D2) ? attS2[col] : 0.f;
    attDv[ni] = (col < D2) ? attD2[col] : 0.f;
  }
  #pragma unroll
  for (int mi=0;mi<2;mi++){
    #pragma unroll
    for (int i=0;i<4;i++){
      int row = m0 + mi*16 + 4*lg + i;
      float pS = 0.f, pD = 0.f;
      #pragma unroll
      for (int ni=0;ni<3;ni++){
        pS += acc[mi][ni][i]*attSv[ni];
        pD += acc[mi][ni][i]*attDv[ni];
      }
      pS += __shfl_xor(pS, 1); pD += __shfl_xor(pD, 1);
      pS += __shfl_xor(pS, 2); pD += __shfl_xor(pD, 2);
      pS += __shfl_xor(pS, 4); pD += __shfl_xor(pD, 4);
      pS += __shfl_xor(pS, 8); pD += __shfl_xor(pD, 8);
      if (row < N){
        #pragma unroll
        for (int ni=0;ni<3;ni++){
          int col = ni*16 + lr;
          if (col < D2) h2b[(size_t)row*D2 + col] = f2bf(acc[mi][ni][i]);
        }
        if (lr == 0){ aS2[row] = pS; aD2[row] = pD; }
      }
    }
  }
}

// ---------------- node1: softmax aggregation over bf16 h1 -> bf16 x2 ----------------
__global__ __launch_bounds__(64) void node1_k(const unsigned short* __restrict__ h1b,
    const float* __restrict__ aS, const float* __restrict__ aD,
    const int* __restrict__ off, const int* __restrict__ csr,
    const float* __restrict__ b1, unsigned short* __restrict__ x2b, int N){
  int n = blockIdx.x;
  int lane = threadIdx.x;
  int c = lane*2;                 // channels c, c+1
  int h = lane >> 3;              // head = c/16
  float ad = aD[n*H1+h];
  float p = __expf(lrelu(aS[n*H1+h] + ad));   // self loop
  float d = p;
  unsigned hv = *(const unsigned*)&h1b[(size_t)n*D1 + c];
  float acc0 = p*bf_lo(hv), acc1 = p*bf_hi(hv);
  int i = off[n], e = off[n+1];
  for (; i < e && (i & 3); ++i){
    int s = csr[i];
    float pp = __expf(lrelu(aS[s*H1+h] + ad));
    unsigned vv = *(const unsigned*)&h1b[(size_t)s*D1 + c];
    d += pp; acc0 += pp*bf_lo(vv); acc1 += pp*bf_hi(vv);
  }
  for (; i+8 <= e; i += 8){
    int4 ca = *(const int4*)&csr[i];
    int4 cb = *(const int4*)&csr[i+4];
    int s[8] = {ca.x,ca.y,ca.z,ca.w,cb.x,cb.y,cb.z,cb.w};
    float a[8]; unsigned v[8];
    #pragma unroll
    for (int u=0;u<8;u++) a[u] = aS[s[u]*H1+h];
    #pragma unroll
    for (int u=0;u<8;u++) v[u] = *(const unsigned*)&h1b[(size_t)s[u]*D1 + c];
    #pragma unroll
    for (int u=0;u<8;u++){
      float pp = __expf(lrelu(a[u]+ad));
      d += pp; acc0 += pp*bf_lo(v[u]); acc1 += pp*bf_hi(v[u]);
    }
  }
  for (; i < e; ++i){
    int s = csr[i];
    float pp = __expf(lrelu(aS[s*H1+h] + ad));
    unsigned vv = *(const unsigned*)&h1b[(size_t)s*D1 + c];
    d += pp; acc0 += pp*bf_lo(vv); acc1 += pp*bf_hi(vv);
  }
  float inv = 1.f/d;
  float o0 = elu(acc0*inv + b1[c]);
  float o1 = elu(acc1*inv + b1[c+1]);
  unsigned pk = (unsigned)f2bf(o0) | ((unsigned)f2bf(o1) << 16);
  *(unsigned*)&x2b[(size_t)n*D1 + c] = pk;
}

// ---------------- node2: 3 nodes per wave (20 lanes each), no cross-lane reduction ----------------
__global__ __launch_bounds__(64) void node2_k(const unsigned short* __restrict__ h2b,
    const float* __restrict__ aS2, const float* __restrict__ aD2,
    const int* __restrict__ off, const int* __restrict__ csr,
    const float* __restrict__ b2, float* __restrict__ out, int N){
  int lane = threadIdx.x;
  int g = lane / 20;              // 0..3 (g==3 idle)
  int l = lane - g*20;            // 0..19
  int n = blockIdx.x*3 + g;
  if (g >= 3 || n >= N) return;
  int c = l*2;
  float ad = aD2[n];
  float ps = __expf(lrelu(aS2[n] + ad));   // self loop
  float d = ps;
  unsigned v0 = *(const unsigned*)&h2b[(size_t)n*D2 + c];
  float acc0 = ps*bf_lo(v0), acc1 = ps*bf_hi(v0);
  int i = off[n], e = off[n+1];
  for (; i < e && (i & 3); ++i){
    int s = csr[i];
    float pp = __expf(lrelu(aS2[s] + ad));
    unsigned vv = *(const unsigned*)&h2b[(size_t)s*D2 + c];
    d += pp; acc0 += pp*bf_lo(vv); acc1 += pp*bf_hi(vv);
  }
  for (; i+8 <= e; i += 8){
    int4 ca = *(const int4*)&csr[i];
    int4 cb = *(const int4*)&csr[i+4];
    int s[8] = {ca.x,ca.y,ca.z,ca.w,cb.x,cb.y,cb.z,cb.w};
    float a[8]; unsigned v[8];
    #pragma unroll
    for (int u=0;u<8;u++) a[u] = aS2[s[u]];
    #pragma unroll
    for (int u=0;u<8;u++) v[u] = *(const unsigned*)&h2b[(size_t)s[u]*D2 + c];
    #pragma unroll
    for (int u=0;u<8;u++){
      float pp = __expf(lrelu(a[u]+ad));
      d += pp; acc0 += pp*bf_lo(v[u]); acc1 += pp*bf_hi(v[u]);
    }
  }
  for (; i < e; ++i){
    int s = csr[i];
    float pp = __expf(lrelu(aS2[s] + ad));
    unsigned vv = *(const unsigned*)&h2b[(size_t)s*D2 + c];
    d += pp; acc0 += pp*bf_lo(vv); acc1 += pp*bf_hi(vv);
  }
  float inv = 1.f/d;
  float2 o;
  o.x = acc0*inv + b2[c];
  o.y = acc1*inv + b2[c+1];
  *(float2*)&out[(size_t)n*D2 + c] = o;
}

extern "C" void kernel_launch(void* const* d_in, const int* in_sizes, int n_in,
                              void* d_out, int out_size, void* d_ws, size_t ws_size,
                              hipStream_t stream){
  const float* x     = (const float*)d_in[0];
  const int*   ei    = (const int*)d_in[1];
  const float* W1    = (const float*)d_in[2];
  const float* attS1 = (const float*)d_in[3];
  const float* attD1 = (const float*)d_in[4];
  const float* b1    = (const float*)d_in[5];
  const float* W2    = (const float*)d_in[6];
  const float* attS2 = (const float*)d_in[7];
  const float* attD2 = (const float*)d_in[8];
  const float* b2    = (const float*)d_in[9];
  float* out = (float*)d_out;

  int N = in_sizes[0] / FIN;   // 50000
  int E = in_sizes[1] / 2;     // 1600000
  const int* src = ei;
  const int* dst = ei + E;
  int NB = (N + BWIDTH - 1) >> BW_LOG;    // 196

  char* ws = (char*)d_ws;
  size_t o = 0;
  auto alloc = [&](size_t bytes) -> void* {
    void* p = ws + o;
    o += (bytes + 255) & ~size_t(255);
    return p;
  };
  unsigned short* h1b = (unsigned short*)alloc((size_t)N*D1*sizeof(unsigned short));
  unsigned short* x2b = (unsigned short*)alloc((size_t)N*D1*sizeof(unsigned short));
  unsigned short* h2b = (unsigned short*)alloc((size_t)N*D2*sizeof(unsigned short));
  float* aS1   = (float*)alloc((size_t)N*H1*sizeof(float));
  float* aD1   = (float*)alloc((size_t)N*H1*sizeof(float));
  float* aS2   = (float*)alloc((size_t)N*sizeof(float));
  float* aD2   = (float*)alloc((size_t)N*sizeof(float));
  int*   off   = (int*)alloc((size_t)(N+1)*sizeof(int));
  int*   csr   = (int*)alloc((size_t)E*sizeof(int));
  int*   blockHist   = (int*)alloc((size_t)NB*B1*sizeof(int));
  int*   wOff        = (int*)alloc((size_t)NB*B1*sizeof(int));
  int*   bucketCnt   = (int*)alloc((size_t)NB*sizeof(int));
  int*   bucketEdges = (int*)alloc((size_t)E*sizeof(int));
  unsigned short* W1T = (unsigned short*)alloc((size_t)D1*FIN*sizeof(unsigned short));
  unsigned short* W2T = (unsigned short*)alloc((size_t)D2P*D1*sizeof(unsigned short));

  int G1 = (N + 63) / 64;      // gemm1 blocks = 782

  f1_k<<<B1 + 128 + 24, 256, 0, stream>>>(dst, E, NB, blockHist, W1, W1T, W2, W2T);
  bscan_k<<<NB, B1, 0, stream>>>(blockHist, wOff, bucketCnt);
  f3_k<<<B1 + G1, 256, 0, stream>>>(x, W1T, attS1, attD1, h1b, aS1, aD1, N,
                                    src, dst, E, NB, bucketCnt, wOff, bucketEdges);
  p2_k<<<NB, BWIDTH, 0, stream>>>(bucketEdges, bucketCnt, NB, off, csr, N);
  node1_k<<<N, 64, 0, stream>>>(h1b, aS1, aD1, off, csr, b1, x2b, N);
  gemm2_mfma<<<(N+127)/128, 256, 0, stream>>>(x2b, W2T, attS2, attD2, h2b, aS2, aD2, N);
  node2_k<<<(N+2)/3, 64, 0, stream>>>(h2b, aS2, aD2, off, csr, b2, out, N);
}

// Round 14
// 184.867 us; speedup vs baseline: 1.2554x; 1.0080x over previous
//
#include <hip/hip_runtime.h>

#define FIN 256
#define H1 8
#define C1 16
#define D1 128   // H1*C1
#define D2 40
#define D2P 48

#define BW_LOG 8
#define BWIDTH 256           // nodes per bucket
#define B1 512               // phase-1 scatter blocks
#define CHMAX 3200           // staging capacity (E/B1 = 3125)

typedef float f32x4 __attribute__((ext_vector_type(4)));
typedef short bf16x8 __attribute__((ext_vector_type(8)));

static __device__ __forceinline__ float lrelu(float x){ return fmaxf(x, 0.2f*x); }
static __device__ __forceinline__ float elu(float x){ return x > 0.f ? x : __expf(x) - 1.f; }
static __device__ __forceinline__ unsigned short f2bf(float f){      // RNE bf16
  unsigned u = __float_as_uint(f);
  return (unsigned short)((u + 0x7fffu + ((u >> 16) & 1u)) >> 16);
}
static __device__ __forceinline__ float bf_lo(unsigned v){ return __uint_as_float(v << 16); }
static __device__ __forceinline__ float bf_hi(unsigned v){ return __uint_as_float(v & 0xffff0000u); }
static __device__ __forceinline__ bf16x8 pack_bf8(float4 a, float4 b){
  bf16x8 r;
  r[0]=(short)f2bf(a.x); r[1]=(short)f2bf(a.y); r[2]=(short)f2bf(a.z); r[3]=(short)f2bf(a.w);
  r[4]=(short)f2bf(b.x); r[5]=(short)f2bf(b.y); r[6]=(short)f2bf(b.z); r[7]=(short)f2bf(b.w);
  return r;
}

// ---------------- F1: p1count (blocks 0..B1) ∪ wt (next 128) ∪ wt2 (next 24) ----------------
__global__ __launch_bounds__(256) void f1_k(const int* __restrict__ dst, int E, int NB,
                                            int* __restrict__ blockHist,
                                            const float* __restrict__ W1, unsigned short* __restrict__ W1T,
                                            const float* __restrict__ W2, unsigned short* __restrict__ W2T){
  int b = blockIdx.x, t = threadIdx.x;
  if (b < B1){
    __shared__ int hist[256];
    hist[t] = 0;
    __syncthreads();
    int CH = (E + B1 - 1) / B1;
    int lo = b*CH, hi = min(E, lo + CH);
    for (int i = lo + t; i < hi; i += 256)
      atomicAdd(&hist[dst[i] >> BW_LOG], 1);
    __syncthreads();
    for (int i = t; i < NB; i += 256) blockHist[i*B1 + b] = hist[i];
  } else if (b < B1 + 128){
    int n = b - B1;
    W1T[n*FIN + t] = f2bf(W1[(size_t)t*D1 + n]);
  } else {
    int c = (b - B1 - 128)*2 + (t >> 7);
    int k = t & 127;
    float v = (c < D2) ? W2[(size_t)k*D2 + c] : 0.f;
    W2T[c*D1 + k] = f2bf(v);
  }
}

// per-bucket exclusive scan over B1 blocks
__global__ __launch_bounds__(B1) void bscan_k(const int* __restrict__ blockHist,
                                              int* __restrict__ wOff, int* __restrict__ bucketCnt){
  __shared__ int s[B1];
  int b = blockIdx.x, t = threadIdx.x;
  int v = blockHist[b*B1 + t];
  s[t] = v; __syncthreads();
  for (int o = 1; o < B1; o <<= 1){
    int u = (t >= o) ? s[t-o] : 0;
    __syncthreads();
    s[t] += u;
    __syncthreads();
  }
  wOff[b*B1 + t] = s[t] - v;
  if (t == B1-1) bucketCnt[b] = s[t];
}

// ---------------- F3: p1scatter staged (blocks 0..B1) ∪ gemm1 (blocks B1..) ----------------
__global__ __launch_bounds__(256) void f3_k(
    // gemm1 args
    const float* __restrict__ x, const unsigned short* __restrict__ W1T,
    const float* __restrict__ attS, const float* __restrict__ attD,
    unsigned short* __restrict__ h1b, float* __restrict__ aS, float* __restrict__ aD, int N,
    // p1scatter args
    const int* __restrict__ src, const int* __restrict__ dst, int E, int NB,
    const int* __restrict__ bucketCnt, const int* __restrict__ wOff, int* __restrict__ bucketEdges){
  int tid = threadIdx.x;
  if ((int)blockIdx.x < B1){
    // ---- p1scatter: block-local bucket sort in LDS, coalesced write-out ----
    __shared__ int sb[256];
    __shared__ int lhist[256];
    __shared__ int lscan[256];
    __shared__ int gbase[256];
    __shared__ int stage[CHMAX];
    __shared__ unsigned char stageB[CHMAX];
    int blk = blockIdx.x;
    // global bucket scan -> per-block global dest base
    int v = (tid < NB) ? bucketCnt[tid] : 0;
    sb[tid] = v; __syncthreads();
    for (int o = 1; o < 256; o <<= 1){
      int u = (tid >= o) ? sb[tid-o] : 0;
      __syncthreads();
      sb[tid] += u;
      __syncthreads();
    }
    if (tid < NB) gbase[tid] = (sb[tid] - v) + wOff[tid*B1 + blk];
    int CH = (E + B1 - 1) / B1;
    int lo = blk*CH, hi = min(E, lo + CH), cnt = hi - lo;
    if (cnt <= CHMAX){
      // local histogram
      lhist[tid] = 0;
      __syncthreads();
      for (int i = lo + tid; i < hi; i += 256)
        atomicAdd(&lhist[dst[i] >> BW_LOG], 1);
      __syncthreads();
      int lv = lhist[tid];
      lscan[tid] = lv; __syncthreads();
      for (int o = 1; o < 256; o <<= 1){
        int u = (tid >= o) ? lscan[tid-o] : 0;
        __syncthreads();
        lscan[tid] += u;
        __syncthreads();
      }
      int excl = lscan[tid] - lv;
      __syncthreads();
      lscan[tid] = excl;           // exclusive scan (slot base per bucket)
      lhist[tid] = excl;           // reuse as cursor
      __syncthreads();
      // scatter into LDS in bucket order
      for (int i = lo + tid; i < hi; i += 256){
        int dd = dst[i];
        int b = dd >> BW_LOG;
        int p = atomicAdd(&lhist[b], 1);
        stage[p] = (src[i] << BW_LOG) | (dd & (BWIDTH-1));
        stageB[p] = (unsigned char)b;
      }
      __syncthreads();
      // coalesced write-out: consecutive slots -> consecutive global addrs per run
      for (int s = tid; s < cnt; s += 256){
        int b = stageB[s];
        bucketEdges[gbase[b] + (s - lscan[b])] = stage[s];
      }
    } else {
      // fallback: direct atomic scatter
      if (tid < NB) lhist[tid] = gbase[tid];
      __syncthreads();
      for (int i = lo + tid; i < hi; i += 256){
        int dd = dst[i];
        int b = dd >> BW_LOG;
        int pos = atomicAdd(&lhist[b], 1);
        bucketEdges[pos] = (src[i] << BW_LOG) | (dd & (BWIDTH-1));
      }
    }
    return;
  }
  // ---- gemm1 ----
  int w = tid >> 6, lane = tid & 63;
  int lr = lane & 15, lg = lane >> 4;
  int wm = w >> 1, wn = w & 1;
  int m0 = ((int)blockIdx.x - B1) * 64;

  int rowA[2];
  #pragma unroll
  for (int mi=0;mi<2;mi++){
    int r = m0 + wm*32 + mi*16 + lr;
    rowA[mi] = (r < N) ? r : (N-1);
  }

  f32x4 acc[2][4];
  #pragma unroll
  for (int mi=0;mi<2;mi++)
    #pragma unroll
    for (int ni=0;ni<4;ni++) acc[mi][ni] = (f32x4){0.f,0.f,0.f,0.f};

  #pragma unroll
  for (int ks = 0; ks < 8; ++ks){
    int k0 = ks*32 + lg*8;
    bf16x8 a[2], b[4];
    #pragma unroll
    for (int mi=0;mi<2;mi++){
      const float* px = x + (size_t)rowA[mi]*FIN + k0;
      float4 v0 = *(const float4*)px;
      float4 v1 = *(const float4*)(px+4);
      a[mi] = pack_bf8(v0, v1);
    }
    #pragma unroll
    for (int ni=0;ni<4;ni++){
      int col = wn*64 + ni*16 + lr;
      b[ni] = *(const bf16x8*)(W1T + (size_t)col*FIN + k0);
    }
    #pragma unroll
    for (int mi=0;mi<2;mi++)
      #pragma unroll
      for (int ni=0;ni<4;ni++)
        acc[mi][ni] = __builtin_amdgcn_mfma_f32_16x16x32_bf16(a[mi], b[ni], acc[mi][ni], 0, 0, 0);
  }

  #pragma unroll
  for (int mi=0;mi<2;mi++){
    #pragma unroll
    for (int ni=0;ni<4;ni++){
      int h = wn*4 + ni;
      int col = wn*64 + ni*16 + lr;
      float sS = attS[h*C1 + lr], sD = attD[h*C1 + lr];
      #pragma unroll
      for (int i=0;i<4;i++){
        int row = m0 + wm*32 + mi*16 + 4*lg + i;
        float v = acc[mi][ni][i];
        float pS = v*sS, pD = v*sD;
        pS += __shfl_xor(pS, 1); pD += __shfl_xor(pD, 1);
        pS += __shfl_xor(pS, 2); pD += __shfl_xor(pD, 2);
        pS += __shfl_xor(pS, 4); pD += __shfl_xor(pD, 4);
        pS += __shfl_xor(pS, 8); pD += __shfl_xor(pD, 8);
        if (row < N){
          h1b[(size_t)row*D1 + col] = f2bf(v);
          if (lr == 0){ aS[row*H1 + h] = pS; aD[row*H1 + h] = pD; }
        }
      }
    }
  }
}

// p2 with inline bucket-count scan; also writes off[N]
__global__ __launch_bounds__(BWIDTH) void p2_k(const int* __restrict__ bucketEdges,
                                               const int* __restrict__ bucketCnt, int NB,
                                               int* __restrict__ off, int* __restrict__ csr, int N){
  __shared__ int deg[BWIDTH];
  __shared__ int s[BWIDTH];
  __shared__ int cur[BWIDTH];
  __shared__ int sb[BWIDTH];
  int b = blockIdx.x, t = threadIdx.x;
  int vc = (t < NB) ? bucketCnt[t] : 0;
  sb[t] = vc; __syncthreads();
  for (int o = 1; o < BWIDTH; o <<= 1){
    int u = (t >= o) ? sb[t-o] : 0;
    __syncthreads();
    sb[t] += u;
    __syncthreads();
  }
  int e0 = (b > 0) ? sb[b-1] : 0;
  int e1 = sb[b];
  if (b == 0 && t == 0) off[N] = sb[NB-1];
  deg[t] = 0;
  __syncthreads();
  for (int i = e0 + t; i < e1; i += BWIDTH)
    atomicAdd(&deg[bucketEdges[i] & (BWIDTH-1)], 1);
  __syncthreads();
  int v = deg[t];
  s[t] = v; __syncthreads();
  for (int o = 1; o < BWIDTH; o <<= 1){
    int u = (t >= o) ? s[t-o] : 0;
    __syncthreads();
    s[t] += u;
    __syncthreads();
  }
  int excl = s[t] - v;
  int node = b*BWIDTH + t;
  if (node < N) off[node] = e0 + excl;
  cur[t] = excl;
  __syncthreads();
  for (int i = e0 + t; i < e1; i += BWIDTH){
    int pk = bucketEdges[i];
    int p = atomicAdd(&cur[pk & (BWIDTH-1)], 1);
    csr[e0 + p] = pk >> BW_LOG;
  }
}

// ---------------- GEMM2 via MFMA, pure bf16 ----------------
__global__ __launch_bounds__(256) void gemm2_mfma(const unsigned short* __restrict__ x2b,
    const unsigned short* __restrict__ W2T,
    const float* __restrict__ attS2, const float* __restrict__ attD2,
    unsigned short* __restrict__ h2b, float* __restrict__ aS2, float* __restrict__ aD2, int N){
  int tid = threadIdx.x;
  int w = tid >> 6, lane = tid & 63;
  int lr = lane & 15, lg = lane >> 4;
  int m0 = blockIdx.x*128 + w*32;

  int rowA[2];
  #pragma unroll
  for (int mi=0;mi<2;mi++){
    int r = m0 + mi*16 + lr;
    rowA[mi] = (r < N) ? r : (N-1);
  }

  f32x4 acc[2][3];
  #pragma unroll
  for (int mi=0;mi<2;mi++)
    #pragma unroll
    for (int ni=0;ni<3;ni++) acc[mi][ni] = (f32x4){0.f,0.f,0.f,0.f};

  #pragma unroll
  for (int ks = 0; ks < 4; ++ks){
    int k0 = ks*32 + lg*8;
    bf16x8 a[2], b[3];
    #pragma unroll
    for (int mi=0;mi<2;mi++)
      a[mi] = *(const bf16x8*)(x2b + (size_t)rowA[mi]*D1 + k0);
    #pragma unroll
    for (int ni=0;ni<3;ni++){
      int col = ni*16 + lr;
      b[ni] = *(const bf16x8*)(W2T + (size_t)col*D1 + k0);
    }
    #pragma unroll
    for (int mi=0;mi<2;mi++)
      #pragma unroll
      for (int ni=0;ni<3;ni++)
        acc[mi][ni] = __builtin_amdgcn_mfma_f32_16x16x32_bf16(a[mi], b[ni], acc[mi][ni], 0, 0, 0);
  }

  float attSv[3], attDv[3];
  #pragma unroll
  for (int ni=0;ni<3;ni++){
    int col = ni*16 + lr;
    attSv[ni] = (col < D2) ? attS2[col] : 0.f;
    attDv[ni] = (col < D2) ? attD2[col] : 0.f;
  }
  #pragma unroll
  for (int mi=0;mi<2;mi++){
    #pragma unroll
    for (int i=0;i<4;i++){
      int row = m0 + mi*16 + 4*lg + i;
      float pS = 0.f, pD = 0.f;
      #pragma unroll
      for (int ni=0;ni<3;ni++){
        pS += acc[mi][ni][i]*attSv[ni];
        pD += acc[mi][ni][i]*attDv[ni];
      }
      pS += __shfl_xor(pS, 1); pD += __shfl_xor(pD, 1);
      pS += __shfl_xor(pS, 2); pD += __shfl_xor(pD, 2);
      pS += __shfl_xor(pS, 4); pD += __shfl_xor(pD, 4);
      pS += __shfl_xor(pS, 8); pD += __shfl_xor(pD, 8);
      if (row < N){
        #pragma unroll
        for (int ni=0;ni<3;ni++){
          int col = ni*16 + lr;
          if (col < D2) h2b[(size_t)row*D2 + col] = f2bf(acc[mi][ni][i]);
        }
        if (lr == 0){ aS2[row] = pS; aD2[row] = pD; }
      }
    }
  }
}

// ---------------- node1: softmax aggregation over bf16 h1 -> bf16 x2 ----------------
__global__ __launch_bounds__(64) void node1_k(const unsigned short* __restrict__ h1b,
    const float* __restrict__ aS, const float* __restrict__ aD,
    const int* __restrict__ off, const int* __restrict__ csr,
    const float* __restrict__ b1, unsigned short* __restrict__ x2b, int N){
  int n = blockIdx.x;
  int lane = threadIdx.x;
  int c = lane*2;                 // channels c, c+1
  int h = lane >> 3;              // head = c/16
  float ad = aD[n*H1+h];
  float p = __expf(lrelu(aS[n*H1+h] + ad));   // self loop
  float d = p;
  unsigned hv = *(const unsigned*)&h1b[(size_t)n*D1 + c];
  float acc0 = p*bf_lo(hv), acc1 = p*bf_hi(hv);
  int i = off[n], e = off[n+1];
  for (; i < e && (i & 3); ++i){
    int s = csr[i];
    float pp = __expf(lrelu(aS[s*H1+h] + ad));
    unsigned vv = *(const unsigned*)&h1b[(size_t)s*D1 + c];
    d += pp; acc0 += pp*bf_lo(vv); acc1 += pp*bf_hi(vv);
  }
  for (; i+8 <= e; i += 8){
    int4 ca = *(const int4*)&csr[i];
    int4 cb = *(const int4*)&csr[i+4];
    int s[8] = {ca.x,ca.y,ca.z,ca.w,cb.x,cb.y,cb.z,cb.w};
    float a[8]; unsigned v[8];
    #pragma unroll
    for (int u=0;u<8;u++) a[u] = aS[s[u]*H1+h];
    #pragma unroll
    for (int u=0;u<8;u++) v[u] = *(const unsigned*)&h1b[(size_t)s[u]*D1 + c];
    #pragma unroll
    for (int u=0;u<8;u++){
      float pp = __expf(lrelu(a[u]+ad));
      d += pp; acc0 += pp*bf_lo(v[u]); acc1 += pp*bf_hi(v[u]);
    }
  }
  for (; i < e; ++i){
    int s = csr[i];
    float pp = __expf(lrelu(aS[s*H1+h] + ad));
    unsigned vv = *(const unsigned*)&h1b[(size_t)s*D1 + c];
    d += pp; acc0 += pp*bf_lo(vv); acc1 += pp*bf_hi(vv);
  }
  float inv = 1.f/d;
  float o0 = elu(acc0*inv + b1[c]);
  float o1 = elu(acc1*inv + b1[c+1]);
  unsigned pk = (unsigned)f2bf(o0) | ((unsigned)f2bf(o1) << 16);
  *(unsigned*)&x2b[(size_t)n*D1 + c] = pk;
}

// ---------------- node2: 3 nodes per wave (20 lanes each), no cross-lane reduction ----------------
__global__ __launch_bounds__(64) void node2_k(const unsigned short* __restrict__ h2b,
    const float* __restrict__ aS2, const float* __restrict__ aD2,
    const int* __restrict__ off, const int* __restrict__ csr,
    const float* __restrict__ b2, float* __restrict__ out, int N){
  int lane = threadIdx.x;
  int g = lane / 20;              // 0..3 (g==3 idle)
  int l = lane - g*20;            // 0..19
  int n = blockIdx.x*3 + g;
  if (g >= 3 || n >= N) return;
  int c = l*2;
  float ad = aD2[n];
  float ps = __expf(lrelu(aS2[n] + ad));   // self loop
  float d = ps;
  unsigned v0 = *(const unsigned*)&h2b[(size_t)n*D2 + c];
  float acc0 = ps*bf_lo(v0), acc1 = ps*bf_hi(v0);
  int i = off[n], e = off[n+1];
  for (; i < e && (i & 3); ++i){
    int s = csr[i];
    float pp = __expf(lrelu(aS2[s] + ad));
    unsigned vv = *(const unsigned*)&h2b[(size_t)s*D2 + c];
    d += pp; acc0 += pp*bf_lo(vv); acc1 += pp*bf_hi(vv);
  }
  for (; i+8 <= e; i += 8){
    int4 ca = *(const int4*)&csr[i];
    int4 cb = *(const int4*)&csr[i+4];
    int s[8] = {ca.x,ca.y,ca.z,ca.w,cb.x,cb.y,cb.z,cb.w};
    float a[8]; unsigned v[8];
    #pragma unroll
    for (int u=0;u<8;u++) a[u] = aS2[s[u]];
    #pragma unroll
    for (int u=0;u<8;u++) v[u] = *(const unsigned*)&h2b[(size_t)s[u]*D2 + c];
    #pragma unroll
    for (int u=0;u<8;u++){
      float pp = __expf(lrelu(a[u]+ad));
      d += pp; acc0 += pp*bf_lo(v[u]); acc1 += pp*bf_hi(v[u]);
    }
  }
  for (; i < e; ++i){
    int s = csr[i];
    float pp = __expf(lrelu(aS2[s] + ad));
    unsigned vv = *(const unsigned*)&h2b[(size_t)s*D2 + c];
    d += pp; acc0 += pp*bf_lo(vv); acc1 += pp*bf_hi(vv);
  }
  float inv = 1.f/d;
  float2 o;
  o.x = acc0*inv + b2[c];
  o.y = acc1*inv + b2[c+1];
  *(float2*)&out[(size_t)n*D2 + c] = o;
}

extern "C" void kernel_launch(void* const* d_in, const int* in_sizes, int n_in,
                              void* d_out, int out_size, void* d_ws, size_t ws_size,
                              hipStream_t stream){
  const float* x     = (const float*)d_in[0];
  const int*   ei    = (const int*)d_in[1];
  const float* W1    = (const float*)d_in[2];
  const float* attS1 = (const float*)d_in[3];
  const float* attD1 = (const float*)d_in[4];
  const float* b1    = (const float*)d_in[5];
  const float* W2    = (const float*)d_in[6];
  const float* attS2 = (const float*)d_in[7];
  const float* attD2 = (const float*)d_in[8];
  const float* b2    = (const float*)d_in[9];
  float* out = (float*)d_out;

  int N = in_sizes[0] / FIN;   // 50000
  int E = in_sizes[1] / 2;     // 1600000
  const int* src = ei;
  const int* dst = ei + E;
  int NB = (N + BWIDTH - 1) >> BW_LOG;    // 196

  char* ws = (char*)d_ws;
  size_t o = 0;
  auto alloc = [&](size_t bytes) -> void* {
    void* p = ws + o;
    o += (bytes + 255) & ~size_t(255);
    return p;
  };
  unsigned short* h1b = (unsigned short*)alloc((size_t)N*D1*sizeof(unsigned short));
  unsigned short* x2b = (unsigned short*)alloc((size_t)N*D1*sizeof(unsigned short));
  unsigned short* h2b = (unsigned short*)alloc((size_t)N*D2*sizeof(unsigned short));
  float* aS1   = (float*)alloc((size_t)N*H1*sizeof(float));
  float* aD1   = (float*)alloc((size_t)N*H1*sizeof(float));
  float* aS2   = (float*)alloc((size_t)N*sizeof(float));
  float* aD2   = (float*)alloc((size_t)N*sizeof(float));
  int*   off   = (int*)alloc((size_t)(N+1)*sizeof(int));
  int*   csr   = (int*)alloc((size_t)E*sizeof(int));
  int*   blockHist   = (int*)alloc((size_t)NB*B1*sizeof(int));
  int*   wOff        = (int*)alloc((size_t)NB*B1*sizeof(int));
  int*   bucketCnt   = (int*)alloc((size_t)NB*sizeof(int));
  int*   bucketEdges = (int*)alloc((size_t)E*sizeof(int));
  unsigned short* W1T = (unsigned short*)alloc((size_t)D1*FIN*sizeof(unsigned short));
  unsigned short* W2T = (unsigned short*)alloc((size_t)D2P*D1*sizeof(unsigned short));

  int G1 = (N + 63) / 64;      // gemm1 blocks = 782

  f1_k<<<B1 + 128 + 24, 256, 0, stream>>>(dst, E, NB, blockHist, W1, W1T, W2, W2T);
  bscan_k<<<NB, B1, 0, stream>>>(blockHist, wOff, bucketCnt);
  f3_k<<<B1 + G1, 256, 0, stream>>>(x, W1T, attS1, attD1, h1b, aS1, aD1, N,
                                    src, dst, E, NB, bucketCnt, wOff, bucketEdges);
  p2_k<<<NB, BWIDTH, 0, stream>>>(bucketEdges, bucketCnt, NB, off, csr, N);
  node1_k<<<N, 64, 0, stream>>>(h1b, aS1, aD1, off, csr, b1, x2b, N);
  gemm2_mfma<<<(N+127)/128, 256, 0, stream>>>(x2b, W2T, attS2, attD2, h2b, aS2, aD2, N);
  node2_k<<<(N+2)/3, 64, 0, stream>>>(h2b, aS2, aD2, off, csr, b2, out, N);
}